// Round 1
// baseline (244.761 us; speedup 1.0000x reference)
//
#include <hip/hip_runtime.h>

#define SCALE 0.0625f  // C^-0.5 = 1/16

typedef __attribute__((ext_vector_type(4))) float f32x4;
typedef __attribute__((ext_vector_type(8))) short s16x8;

__device__ __forceinline__ unsigned short f2bf(float x) {
    unsigned u = __float_as_uint(x);
    u = u + 0x7FFF + ((u >> 16) & 1);   // RNE; inputs finite
    return (unsigned short)(u >> 16);
}

// ---------------------------------------------------------------------------
// prep1: blocks 0..15  -> q[b,c] = TO[b] . Wq[c] + bq[c]
//        blocks 16..31 -> WvB = bf16(Wv)   (row-major [co][o], no transpose)
// ---------------------------------------------------------------------------
__global__ __launch_bounds__(256) void prep1_kernel(
    const float* __restrict__ TO,    // [2,1024]
    const float* __restrict__ Wq,    // [256,1024]
    const float* __restrict__ bq,    // [256]
    const float* __restrict__ Wv,    // [256,256]
    float* __restrict__ qbuf,        // [2,256]
    unsigned short* __restrict__ WvB)// [256,256] bf16
{
    const int blk = blockIdx.x;
    const int t   = threadIdx.x;
    if (blk < 16) {
        const int b    = blk >> 3;
        const int rblk = blk & 7;
        const int wv = t >> 6, l = t & 63;
        const float4* Wq4 = (const float4*)Wq;
        const float4* TO4 = (const float4*)TO;
        for (int rr = 0; rr < 8; ++rr) {
            const int c = rblk * 32 + wv * 8 + rr;
            float acc = 0.f;
#pragma unroll
            for (int i = 0; i < 4; ++i) {
                float4 wq = Wq4[c * 256 + i * 64 + l];
                float4 tv = TO4[b * 256 + i * 64 + l];
                acc = fmaf(wq.x, tv.x, acc);
                acc = fmaf(wq.y, tv.y, acc);
                acc = fmaf(wq.z, tv.z, acc);
                acc = fmaf(wq.w, tv.w, acc);
            }
#pragma unroll
            for (int mask = 1; mask < 64; mask <<= 1)
                acc += __shfl_xor(acc, mask, 64);
            if (l == 0) qbuf[b * 256 + c] = acc + bq[c];
        }
    } else {
        const int idx = blk - 16;   // 0..15, 4096 elements each
#pragma unroll
        for (int i = 0; i < 4; ++i) {
            const int e = idx * 4096 + i * 1024 + t * 4;
            const float4 f = ((const float4*)Wv)[e >> 2];
            ushort4 o;
            o.x = f2bf(f.x); o.y = f2bf(f.y);
            o.z = f2bf(f.z); o.w = f2bf(f.w);
            *(ushort4*)(WvB + e) = o;
        }
    }
}

// ---------------------------------------------------------------------------
// prep2: 16 blocks: qks[b,cp] = SCALE * sum_c q[c] Wk[c][cp]
// (q.bk term dropped: softmax-invariant)
// ---------------------------------------------------------------------------
__global__ __launch_bounds__(256) void prep2_kernel(
    const float* __restrict__ qbuf,  // [2,256]
    const float* __restrict__ Wk,    // [256,256]
    float* __restrict__ qks)         // [2,256] (pre-scaled)
{
    const int blk = blockIdx.x;
    const int t   = threadIdx.x;
    const int b = blk >> 3, j = blk & 7;
    const int col = t & 31, chunk = t >> 5;
    const int cp = j * 32 + col;
    float partial = 0.f;
#pragma unroll 8
    for (int cc = 0; cc < 32; ++cc) {
        const int c = chunk * 32 + cc;
        partial = fmaf(qbuf[b * 256 + c], Wk[c * 256 + cp], partial);
    }
    __shared__ float r2[8][32];
    r2[chunk][col] = partial;
    __syncthreads();
    if (t < 32) {
        float s = 0.f;
#pragma unroll
        for (int k = 0; k < 8; ++k) s += r2[k][t];
        qks[b * 256 + j * 32 + t] = SCALE * s;
    }
}

// ---------------------------------------------------------------------------
// main: 512 blocks x 256 thr (4 waves). Block owns 16 pixels x 256 channels;
//   wave w owns maps m = 4w..4w+3 (m-split: softmax partials are linear
//   because we accumulate UNNORMALIZED exp(s)-weighted sums + partial lsum).
//   Per wave identical to the proven 1-wave structure: lane = p4(0..3) +
//   4*cg(0..15); 16 dwordx4 loads per m (64B-contiguous per (cg,k)),
//   register double-buffer, 4-stage shfl_xor score reduce, no barriers in
//   the m-loop. Occupancy: 2048 waves = 8/CU (vs 512 = 2/CU before).
// Combine: waves 1,2 -> scratch slabs; wave 3 -> slab (aliased scratch);
//   wave 0 folds all + its own regs, normalizes, writes final slab.
//   2 barriers total. LDS = 60.3 KB -> 2 blocks/CU fits (120.6 <= 160 KB).
// Epilogue: bf16 MFMA 16x16x32 conv vs WvB + bv, co-tiles split 4-ways
//   across the waves (wave w does tt = 4w..4w+3).
// ---------------------------------------------------------------------------
__global__ __launch_bounds__(256, 2) void main_kernel(
    const float* __restrict__ X,     // [2,16,256,4096]
    const float* __restrict__ qks,   // [2,256]
    const unsigned short* __restrict__ WvB,  // [256,256] bf16, row-major co x o
    const float* __restrict__ bv,    // [256]
    float* __restrict__ out)         // [2,256,4096]
{
    const int t    = threadIdx.x;    // 0..255
    const int lane = t & 63;
    const int w    = t >> 6;         // wave id: maps 4w..4w+3
    const int blk  = blockIdx.x;     // 0..511
    const int pb   = ((blk & 7) << 6) | (blk >> 3);   // XCD swizzle
    const int b    = pb >> 8;
    const int hw0  = (pb & 255) << 4; // 16 pixels
    const int p4   = lane & 3;       // pixel quartet within the 16
    const int cg   = lane >> 2;      // 0..15 channel group

    // LDS map (floats): s1 @0, s2 @5120, slab/s3 @10240, lsums @15360
    __shared__ float smem[15360 + 64];
    float* const s1    = smem;
    float* const s2    = smem + 5120;
    float* const slab  = smem + 10240;  // wave3 scratch aliases final slab
    float* const lsums = smem + 15360;  // [4 waves][16 px]

    float qk[16];
#pragma unroll
    for (int k = 0; k < 16; ++k) qk[k] = qks[b * 256 + cg + 16 * k];

    const float4* X4 = (const float4*)X;
    // base for this wave's first map (m = 4w)
    const int base0 = (b * 16 + w * 4) * 262144 + (hw0 >> 2) + p4;

    float4 v[2][16];
    float4 wx[16];
#pragma unroll
    for (int k = 0; k < 16; ++k) wx[k] = make_float4(0.f, 0.f, 0.f, 0.f);
    float lsum[4] = {0.f, 0.f, 0.f, 0.f};

#pragma unroll
    for (int k = 0; k < 16; ++k)
        v[0][k] = X4[base0 + (cg + 16 * k) * 1024];

#pragma unroll
    for (int i = 0; i < 4; ++i) {      // this wave's 4 maps
        const int buf = i & 1, nxt = buf ^ 1;
        if (i < 3) {
#pragma unroll
            for (int k = 0; k < 16; ++k)
                v[nxt][k] = X4[base0 + (i + 1) * 262144 + (cg + 16 * k) * 1024];
        }
        float sx = 0.f, sy = 0.f, sz = 0.f, sw = 0.f;
#pragma unroll
        for (int k = 0; k < 16; ++k) {
            sx = fmaf(qk[k], v[buf][k].x, sx);
            sy = fmaf(qk[k], v[buf][k].y, sy);
            sz = fmaf(qk[k], v[buf][k].z, sz);
            sw = fmaf(qk[k], v[buf][k].w, sw);
        }
#pragma unroll
        for (int mask = 4; mask < 64; mask <<= 1) {
            sx += __shfl_xor(sx, mask, 64);
            sy += __shfl_xor(sy, mask, 64);
            sz += __shfl_xor(sz, mask, 64);
            sw += __shfl_xor(sw, mask, 64);
        }
        const float w0 = __expf(sx), w1 = __expf(sy);
        const float w2 = __expf(sz), w3 = __expf(sw);
        lsum[0] += w0; lsum[1] += w1; lsum[2] += w2; lsum[3] += w3;
#pragma unroll
        for (int k = 0; k < 16; ++k) {
            wx[k].x = fmaf(w0, v[buf][k].x, wx[k].x);
            wx[k].y = fmaf(w1, v[buf][k].y, wx[k].y);
            wx[k].z = fmaf(w2, v[buf][k].z, wx[k].z);
            wx[k].w = fmaf(w3, v[buf][k].w, wx[k].w);
        }
    }

    // ---- cross-wave combine of partial softmax sums ----
    if (w != 0) {
        float* dst = (w == 1) ? s1 : (w == 2) ? s2 : slab;
#pragma unroll
        for (int k = 0; k < 16; ++k)
            *(float4*)&dst[(cg + 16 * k) * 20 + 4 * p4] = wx[k];
    }
    if (cg == 0) {   // lanes 0..3 of each wave hold lsum for their quartet
#pragma unroll
        for (int j = 0; j < 4; ++j) lsums[w * 16 + p4 * 4 + j] = lsum[j];
    }
    __syncthreads();

    if (w == 0) {
        float inv[4];
#pragma unroll
        for (int j = 0; j < 4; ++j) {
            const int px = p4 * 4 + j;
            const float tot = lsums[px] + lsums[16 + px] +
                              lsums[32 + px] + lsums[48 + px];
            inv[j] = 1.0f / tot;
        }
#pragma unroll
        for (int k = 0; k < 16; ++k) {
            const int i = (cg + 16 * k) * 20 + 4 * p4;
            const float4 a = *(const float4*)&s1[i];
            const float4 c = *(const float4*)&s2[i];
            const float4 d = *(const float4*)&slab[i];  // read before write
            float4 r;
            r.x = (wx[k].x + a.x + c.x + d.x) * inv[0];
            r.y = (wx[k].y + a.y + c.y + d.y) * inv[1];
            r.z = (wx[k].z + a.z + c.z + d.z) * inv[2];
            r.w = (wx[k].w + a.w + c.w + d.w) * inv[3];
            *(float4*)&slab[i] = r;   // in-place, same element per lane
        }
    }
    __syncthreads();

    // epilogue: out[co, px] = bv[co] + sum_o Wv[co][o] * wx[o][px]  via MFMA
    // D tile = 16co x 16px; wave w handles co-tiles tt = 4w..4w+3
    const int px   = lane & 15;    // D col / A row-select / B col
    const int quad = lane >> 4;    // 0..3

    f32x4 acc[4];
#pragma unroll
    for (int tl = 0; tl < 4; ++tl) {
        const int tt = w * 4 + tl;
#pragma unroll
        for (int r = 0; r < 4; ++r)
            acc[tl][r] = bv[16 * tt + quad * 4 + r];
    }

#pragma unroll
    for (int ks = 0; ks < 8; ++ks) {   // K = 256 in steps of 32
        s16x8 bfr;
#pragma unroll
        for (int j = 0; j < 8; ++j)
            bfr[j] = (short)f2bf(slab[(ks * 32 + quad * 8 + j) * 20 + px]);
#pragma unroll
        for (int tl = 0; tl < 4; ++tl) {
            const int tt = w * 4 + tl;
            const s16x8 afr =
                *(const s16x8*)(WvB + (16 * tt + px) * 256 + ks * 32 + quad * 8);
            acc[tl] = __builtin_amdgcn_mfma_f32_16x16x32_bf16(afr, bfr, acc[tl],
                                                              0, 0, 0);
        }
    }

    const int obase = b * 256 * 4096 + hw0;
#pragma unroll
    for (int tl = 0; tl < 4; ++tl) {
#pragma unroll
        for (int r = 0; r < 4; ++r) {
            const int co = 16 * (w * 4 + tl) + quad * 4 + r;
            out[obase + co * 4096 + px] = acc[tl][r];
        }
    }
}

// ---------------------------------------------------------------------------
extern "C" void kernel_launch(void* const* d_in, const int* in_sizes, int n_in,
                              void* d_out, int out_size, void* d_ws, size_t ws_size,
                              hipStream_t stream) {
    const float* TO = (const float*)d_in[0];   // [2,1024]
    const float* X  = (const float*)d_in[1];   // [2,16,256,64,64]
    const float* Wq = (const float*)d_in[2];   // [256,1024]
    const float* bq = (const float*)d_in[3];   // [256]
    const float* Wk = (const float*)d_in[4];   // [256,256]
    // d_in[5] = bk: dropped (softmax-invariant)
    const float* Wv = (const float*)d_in[6];   // [256,256]
    const float* bv = (const float*)d_in[7];   // [256]
    float* out = (float*)d_out;
    float* ws  = (float*)d_ws;

    float*          qbuf = ws;                              // 512 floats
    float*          qks  = ws + 512;                        // 512 floats
    unsigned short* WvB  = (unsigned short*)(ws + 1024);    // 65536 bf16

    hipLaunchKernelGGL(prep1_kernel, dim3(32), dim3(256), 0, stream,
                       TO, Wq, bq, Wv, qbuf, WvB);
    hipLaunchKernelGGL(prep2_kernel, dim3(16), dim3(256), 0, stream,
                       qbuf, Wk, qks);
    hipLaunchKernelGGL(main_kernel, dim3(512), dim3(256), 0, stream,
                       X, qks, WvB, bv, out);
}

// Round 2
// 234.677 us; speedup vs baseline: 1.0430x; 1.0430x over previous
//
#include <hip/hip_runtime.h>

#define SCALE 0.0625f  // C^-0.5 = 1/16
#define ROW 36         // dwords per c-row in LDS tile (32 px + 4 pad)

typedef __attribute__((ext_vector_type(4))) float f32x4;
typedef __attribute__((ext_vector_type(8))) short s16x8;

__device__ __forceinline__ unsigned short f2bf(float x) {
    unsigned u = __float_as_uint(x);
    u = u + 0x7FFF + ((u >> 16) & 1);   // RNE; inputs finite
    return (unsigned short)(u >> 16);
}

// ---------------------------------------------------------------------------
// prep1: blocks 0..15  -> q[b,c] = TO[b] . Wq[c] + bq[c]
//        blocks 16..31 -> WvB = bf16(Wv)   (row-major [co][o], no transpose)
// ---------------------------------------------------------------------------
__global__ __launch_bounds__(256) void prep1_kernel(
    const float* __restrict__ TO,    // [2,1024]
    const float* __restrict__ Wq,    // [256,1024]
    const float* __restrict__ bq,    // [256]
    const float* __restrict__ Wv,    // [256,256]
    float* __restrict__ qbuf,        // [2,256]
    unsigned short* __restrict__ WvB)// [256,256] bf16
{
    const int blk = blockIdx.x;
    const int t   = threadIdx.x;
    if (blk < 16) {
        const int b    = blk >> 3;
        const int rblk = blk & 7;
        const int wv = t >> 6, l = t & 63;
        const float4* Wq4 = (const float4*)Wq;
        const float4* TO4 = (const float4*)TO;
        for (int rr = 0; rr < 8; ++rr) {
            const int c = rblk * 32 + wv * 8 + rr;
            float acc = 0.f;
#pragma unroll
            for (int i = 0; i < 4; ++i) {
                float4 wq = Wq4[c * 256 + i * 64 + l];
                float4 tv = TO4[b * 256 + i * 64 + l];
                acc = fmaf(wq.x, tv.x, acc);
                acc = fmaf(wq.y, tv.y, acc);
                acc = fmaf(wq.z, tv.z, acc);
                acc = fmaf(wq.w, tv.w, acc);
            }
#pragma unroll
            for (int mask = 1; mask < 64; mask <<= 1)
                acc += __shfl_xor(acc, mask, 64);
            if (l == 0) qbuf[b * 256 + c] = acc + bq[c];
        }
    } else {
        const int idx = blk - 16;   // 0..15, 4096 elements each
#pragma unroll
        for (int i = 0; i < 4; ++i) {
            const int e = idx * 4096 + i * 1024 + t * 4;
            const float4 f = ((const float4*)Wv)[e >> 2];
            ushort4 o;
            o.x = f2bf(f.x); o.y = f2bf(f.y);
            o.z = f2bf(f.z); o.w = f2bf(f.w);
            *(ushort4*)(WvB + e) = o;
        }
    }
}

// ---------------------------------------------------------------------------
// prep2: 16 blocks: qks[b,cp] = SCALE * sum_c q[c] Wk[c][cp]
// (q.bk term dropped: softmax-invariant)
// ---------------------------------------------------------------------------
__global__ __launch_bounds__(256) void prep2_kernel(
    const float* __restrict__ qbuf,  // [2,256]
    const float* __restrict__ Wk,    // [256,256]
    float* __restrict__ qks)         // [2,256] (pre-scaled)
{
    const int blk = blockIdx.x;
    const int t   = threadIdx.x;
    const int b = blk >> 3, j = blk & 7;
    const int col = t & 31, chunk = t >> 5;
    const int cp = j * 32 + col;
    float partial = 0.f;
#pragma unroll 8
    for (int cc = 0; cc < 32; ++cc) {
        const int c = chunk * 32 + cc;
        partial = fmaf(qbuf[b * 256 + c], Wk[c * 256 + cp], partial);
    }
    __shared__ float r2[8][32];
    r2[chunk][col] = partial;
    __syncthreads();
    if (t < 32) {
        float s = 0.f;
#pragma unroll
        for (int k = 0; k < 8; ++k) s += r2[k][t];
        qks[b * 256 + j * 32 + t] = SCALE * s;
    }
}

// ---------------------------------------------------------------------------
// main: 256 blocks x 512 thr (8 waves). Block owns 32 px (128 B = full
//   aligned cache lines per (m,c) row). Per map: stage 256c x 32px (32 KB)
//   to LDS via contiguous dwordx4 (8 FULL 128-B lines per instruction, vs
//   the old 16 half-lines -> 2x line utilization, 2x fewer requests/byte).
//   T14 async-split: issue next map's loads -> compute current from LDS ->
//   ds_write. One barrier per map, double-buffered LDS (2x36 KB).
// Compute: wave w owns px quartet w*4..w*4+3, lane owns c in {l,l+64,
//   l+128,l+192}. Scores via full-wave shfl_xor butterfly (all lanes end
//   with all 4 px scores); max-free softmax; wx[4] float4 in regs.
//   LDS rows padded to 36 dwords + c-stride-64 -> conflict-clean ds ops.
// Epilogue: normalized wx -> buf0 slab; bf16 MFMA 16x16x32 vs WvB + bv;
//   wave w does co-tiles 2w..2w+1 x both px-halves.
// ---------------------------------------------------------------------------
__global__ __launch_bounds__(512, 2) void main_kernel(
    const float* __restrict__ X,     // [2,16,256,4096]
    const float* __restrict__ qks,   // [2,256]
    const unsigned short* __restrict__ WvB,  // [256,256] bf16, row-major co x o
    const float* __restrict__ bv,    // [256]
    float* __restrict__ out)         // [2,256,4096]
{
    const int t    = threadIdx.x;    // 0..511
    const int lane = t & 63;
    const int w    = t >> 6;         // wave 0..7
    const int blk  = blockIdx.x;     // 0..255
    const int b    = blk >> 7;
    const int hw0  = (blk & 127) << 5;   // 32 px, 128-B aligned

    __shared__ float lds[2 * 256 * ROW];  // 73728 B
    float* const buf0 = lds;
    float* const buf1 = lds + 256 * ROW;

    // ---- staging thread-map: thread t covers (c = sc + 64r, px-quartet spxq)
    const int sc   = t >> 3;        // 0..63
    const int spxq = t & 7;         // 0..7
    const float4* X4 = (const float4*)X;
    const int gstage = b * 16 * 262144 + (hw0 >> 2) + spxq;  // + m*262144 + c*1024

    // ---- compute thread-map: lane owns c = lane + 64*c4, wave px = w*4..+3
    float qk[4];
#pragma unroll
    for (int c4 = 0; c4 < 4; ++c4)
        qk[c4] = qks[b * 256 + lane + 64 * c4];

    float4 wx[4];
#pragma unroll
    for (int c4 = 0; c4 < 4; ++c4) wx[c4] = make_float4(0.f, 0.f, 0.f, 0.f);
    float lsx = 0.f, lsy = 0.f, lsz = 0.f, lsw = 0.f;

    float4 sreg[4];
#pragma unroll
    for (int r = 0; r < 4; ++r)
        sreg[r] = X4[gstage + 0 * 262144 + (sc + r * 64) * 1024];
#pragma unroll
    for (int r = 0; r < 4; ++r)
        *(float4*)&buf0[(sc + r * 64) * ROW + spxq * 4] = sreg[r];

#pragma unroll 2
    for (int m = 0; m < 16; ++m) {
        __syncthreads();   // buf[m&1] writes visible; prev readers of buf[(m+1)&1] done
        float* const cur  = (m & 1) ? buf1 : buf0;
        float* const nxtb = (m & 1) ? buf0 : buf1;

        if (m < 15) {      // issue next map's loads early (latency hides under compute)
#pragma unroll
            for (int r = 0; r < 4; ++r)
                sreg[r] = X4[gstage + (m + 1) * 262144 + (sc + r * 64) * 1024];
        }

        // compute map m from cur
        float4 v[4];
#pragma unroll
        for (int c4 = 0; c4 < 4; ++c4)
            v[c4] = *(const float4*)&cur[(lane + 64 * c4) * ROW + w * 4];

        float sx = 0.f, sy = 0.f, sz = 0.f, sw = 0.f;
#pragma unroll
        for (int c4 = 0; c4 < 4; ++c4) {
            sx = fmaf(qk[c4], v[c4].x, sx);
            sy = fmaf(qk[c4], v[c4].y, sy);
            sz = fmaf(qk[c4], v[c4].z, sz);
            sw = fmaf(qk[c4], v[c4].w, sw);
        }
#pragma unroll
        for (int mask = 1; mask < 64; mask <<= 1) {
            sx += __shfl_xor(sx, mask, 64);
            sy += __shfl_xor(sy, mask, 64);
            sz += __shfl_xor(sz, mask, 64);
            sw += __shfl_xor(sw, mask, 64);
        }
        const float e0 = __expf(sx), e1 = __expf(sy);
        const float e2 = __expf(sz), e3 = __expf(sw);
        lsx += e0; lsy += e1; lsz += e2; lsw += e3;
#pragma unroll
        for (int c4 = 0; c4 < 4; ++c4) {
            wx[c4].x = fmaf(e0, v[c4].x, wx[c4].x);
            wx[c4].y = fmaf(e1, v[c4].y, wx[c4].y);
            wx[c4].z = fmaf(e2, v[c4].z, wx[c4].z);
            wx[c4].w = fmaf(e3, v[c4].w, wx[c4].w);
        }

        if (m < 15) {      // park next map's tile (write-after-read safe: see barrier)
#pragma unroll
            for (int r = 0; r < 4; ++r)
                *(float4*)&nxtb[(sc + r * 64) * ROW + spxq * 4] = sreg[r];
        }
    }

    // ---- normalize, park wx in slab (= buf0; its map-14 readers are long done)
    const float i0 = 1.0f / lsx, i1 = 1.0f / lsy;
    const float i2 = 1.0f / lsz, i3 = 1.0f / lsw;
#pragma unroll
    for (int c4 = 0; c4 < 4; ++c4) {
        float4 r;
        r.x = wx[c4].x * i0; r.y = wx[c4].y * i1;
        r.z = wx[c4].z * i2; r.w = wx[c4].w * i3;
        *(float4*)&buf0[(lane + 64 * c4) * ROW + w * 4] = r;
    }
    __syncthreads();

    // ---- epilogue: out[co,px] = bv[co] + sum_o Wv[co][o] * wx[o][px] via MFMA
    // wave w: co-tiles tt = 2w, 2w+1; both 16-px halves of the 32 px.
    const int px16 = lane & 15;
    const int quad = lane >> 4;

    f32x4 acc[2][2];   // [tl][pxh]
#pragma unroll
    for (int tl = 0; tl < 2; ++tl)
#pragma unroll
        for (int pxh = 0; pxh < 2; ++pxh)
#pragma unroll
            for (int r = 0; r < 4; ++r)
                acc[tl][pxh][r] = bv[16 * (w * 2 + tl) + quad * 4 + r];

#pragma unroll
    for (int ks = 0; ks < 8; ++ks) {   // K = 256 in steps of 32
        s16x8 bfr[2];
#pragma unroll
        for (int pxh = 0; pxh < 2; ++pxh)
#pragma unroll
            for (int j = 0; j < 8; ++j)
                bfr[pxh][j] = (short)f2bf(
                    buf0[(ks * 32 + quad * 8 + j) * ROW + pxh * 16 + px16]);
#pragma unroll
        for (int tl = 0; tl < 2; ++tl) {
            const s16x8 afr = *(const s16x8*)(
                WvB + (16 * (w * 2 + tl) + px16) * 256 + ks * 32 + quad * 8);
#pragma unroll
            for (int pxh = 0; pxh < 2; ++pxh)
                acc[tl][pxh] = __builtin_amdgcn_mfma_f32_16x16x32_bf16(
                    afr, bfr[pxh], acc[tl][pxh], 0, 0, 0);
        }
    }

    const int obase = b * 256 * 4096 + hw0;
#pragma unroll
    for (int tl = 0; tl < 2; ++tl)
#pragma unroll
        for (int pxh = 0; pxh < 2; ++pxh)
#pragma unroll
            for (int r = 0; r < 4; ++r) {
                const int co = 16 * (w * 2 + tl) + quad * 4 + r;
                out[obase + co * 4096 + pxh * 16 + px16] = acc[tl][pxh][r];
            }
}

// ---------------------------------------------------------------------------
extern "C" void kernel_launch(void* const* d_in, const int* in_sizes, int n_in,
                              void* d_out, int out_size, void* d_ws, size_t ws_size,
                              hipStream_t stream) {
    const float* TO = (const float*)d_in[0];   // [2,1024]
    const float* X  = (const float*)d_in[1];   // [2,16,256,64,64]
    const float* Wq = (const float*)d_in[2];   // [256,1024]
    const float* bq = (const float*)d_in[3];   // [256]
    const float* Wk = (const float*)d_in[4];   // [256,256]
    // d_in[5] = bk: dropped (softmax-invariant)
    const float* Wv = (const float*)d_in[6];   // [256,256]
    const float* bv = (const float*)d_in[7];   // [256]
    float* out = (float*)d_out;
    float* ws  = (float*)d_ws;

    float*          qbuf = ws;                              // 512 floats
    float*          qks  = ws + 512;                        // 512 floats
    unsigned short* WvB  = (unsigned short*)(ws + 1024);    // 65536 bf16

    hipLaunchKernelGGL(prep1_kernel, dim3(32), dim3(256), 0, stream,
                       TO, Wq, bq, Wv, qbuf, WvB);
    hipLaunchKernelGGL(prep2_kernel, dim3(16), dim3(256), 0, stream,
                       qbuf, Wk, qks);
    hipLaunchKernelGGL(main_kernel, dim3(256), dim3(512), 0, stream,
                       X, qks, WvB, bv, out);
}